// Round 4
// baseline (119.228 us; speedup 1.0000x reference)
//
#include <hip/hip_runtime.h>
#include <math.h>

#define NPOS 1024   // H*W
#define DH   32     // dim head
#define NBH  8      // B * HEADS
#define CH   256
#define INNER 128   // HEADS*DIM_HEAD
#define SPLITS 16   // m-splits
#define MBLK (NPOS / SPLITS)   // 64 keys per WG
#define MT   16     // m-tile width (register tile)

// ---------------------------------------------------------------------------
// Kernel A: fused QKV projection, NATURAL layout.
// Q/K/V[bh][d][n] = sum_c W[i,c] * x[b,c,n],  i = (bh&3... ) h*32+d.
// Q pre-scaled by 1/sqrt(dh).
// ---------------------------------------------------------------------------
__global__ __launch_bounds__(256) void proj_kernel(
    const float* __restrict__ x, const float* __restrict__ Wq,
    const float* __restrict__ Wk, const float* __restrict__ Wv,
    float* __restrict__ Q, float* __restrict__ K, float* __restrict__ V)
{
  const int lane = threadIdx.x & 63;
  const int it   = threadIdx.x >> 6;        // 0..3
  const int n    = blockIdx.x * 64 + lane;  // 0..1023
  const int i0   = blockIdx.y * 8 + it * 2; // even, 0..126
  const int b    = blockIdx.z;

  const float* xb = x  + (size_t)b * CH * NPOS + n;
  const float* wq = Wq + (size_t)i0 * CH;
  const float* wk = Wk + (size_t)i0 * CH;
  const float* wv = Wv + (size_t)i0 * CH;

  float aq0 = 0.f, aq1 = 0.f, ak0 = 0.f, ak1 = 0.f, av0 = 0.f, av1 = 0.f;

  #pragma unroll 16
  for (int c = 0; c < CH; ++c) {
    float xv = xb[(size_t)c * NPOS];
    aq0 += wq[c]      * xv;
    aq1 += wq[CH + c] * xv;
    ak0 += wk[c]      * xv;
    ak1 += wk[CH + c] * xv;
    av0 += wv[c]      * xv;
    av1 += wv[CH + c] * xv;
  }

  const float qs = 0.17677669529663687f;  // 1/sqrt(32), folded into Q
  // natural layout: [(b*4+h)*32 + d][n]
  const size_t base = ((size_t)(b * 4 + (i0 >> 5)) * DH + (i0 & 31)) * NPOS + n;
  Q[base]        = aq0 * qs;
  Q[base + NPOS] = aq1 * qs;
  K[base]        = ak0;
  K[base + NPOS] = ak1;
  V[base]        = av0;
  V[base + NPOS] = av1;
}

// ---------------------------------------------------------------------------
// Kernel B: fused scores -> KAN -> fixed-bound exp -> PV.
// Thread = q row. K/V read at wave-uniform addresses (-> s_load / SGPR
// operands in the FMAs); no LDS, no shuffles, no spline table gathers.
// ---------------------------------------------------------------------------
__global__ __launch_bounds__(256) void attn_kernel(
    const float* __restrict__ Q, const float* __restrict__ K,
    const float* __restrict__ V,
    const float* __restrict__ bwp, const float* __restrict__ swp,
    const float* __restrict__ ssp,
    float* __restrict__ Oacc, float* __restrict__ Sden)
{
  const int tid = threadIdx.x;
  const int bh  = blockIdx.x;   // 0..7
  const int rb  = blockIdx.y;   // 0..3
  const int sp  = blockIdx.z;   // 0..SPLITS-1
  const int row = rb * 256 + tid;

  // ---- uniform KAN constants (scalar pipe) ----
  const float sc = ssp[0];
  const float bw = bwp[0];
  float C[8];
  #pragma unroll
  for (int j = 0; j < 8; ++j) C[j] = swp[j] * sc;
  float maxc = 0.f;
  #pragma unroll
  for (int j = 0; j < 8; ++j) maxc = fmaxf(maxc, fabsf(C[j]));
  const float Bnd = fabsf(bw) * 6.0f + maxc;   // >= max_x kan(x)

  // per-cell cubic coefs in u; -Bnd folded into a0
  float A0[5], A1[5], A2[5], A3[5];
  #pragma unroll
  for (int c = 0; c < 5; ++c) {
    A0[c] = (C[c] + 4.f * C[c+1] + C[c+2]) * (1.f / 6.f) - Bnd;
    A1[c] = (-3.f * C[c] + 3.f * C[c+2]) * (1.f / 6.f);
    A2[c] = (3.f * C[c] - 6.f * C[c+1] + 3.f * C[c+2]) * (1.f / 6.f);
    A3[c] = (-C[c] + 3.f * C[c+1] - 3.f * C[c+2] + C[c+3]) * (1.f / 6.f);
  }

  // ---- load own q row (coalesced across lanes: lane-consecutive n) ----
  const float* Qb = Q + (size_t)bh * DH * NPOS + row;
  float q[DH];
  #pragma unroll
  for (int d = 0; d < DH; ++d) q[d] = Qb[(size_t)d * NPOS];

  float o[DH];
  #pragma unroll
  for (int d = 0; d < DH; ++d) o[d] = 0.f;
  float ssum = 0.f;

  const float* Kb = K + (size_t)bh * DH * NPOS;
  const float* Vb = V + (size_t)bh * DH * NPOS;

  for (int t0 = sp * MBLK; t0 < sp * MBLK + MBLK; t0 += MT) {
    // ---- QK: s[m] += q[d] * K[d][t0+m]  (K uniform -> SGPR broadcast) ----
    float s[MT];
    #pragma unroll
    for (int m = 0; m < MT; ++m) s[m] = 0.f;
    #pragma unroll
    for (int d = 0; d < DH; ++d) {
      const float* kr = Kb + (size_t)d * NPOS + t0;
      #pragma unroll
      for (int m = 0; m < MT; ++m) s[m] = fmaf(q[d], kr[m], s[m]);
    }

    // ---- KAN + exp(kan - Bnd) per element ----
    float p[MT];
    #pragma unroll
    for (int m = 0; m < MT; ++m) {
      float sv = fminf(fmaxf(s[m], -6.0f), 6.0f);
      float e   = __expf(-sv);
      float sil = sv * __builtin_amdgcn_rcpf(1.0f + e);
      float t  = fmaf(sv, (1.0f / 2.4f), 2.5f);   // (sv+6)/2.4 in [0,5]
      float cf = fminf(floorf(t), 4.0f);
      float u  = t - cf;
      float a0 = A0[0], a1 = A1[0], a2 = A2[0], a3 = A3[0];
      a0 = cf >= 0.5f ? A0[1] : a0;  a1 = cf >= 0.5f ? A1[1] : a1;
      a2 = cf >= 0.5f ? A2[1] : a2;  a3 = cf >= 0.5f ? A3[1] : a3;
      a0 = cf >= 1.5f ? A0[2] : a0;  a1 = cf >= 1.5f ? A1[2] : a1;
      a2 = cf >= 1.5f ? A2[2] : a2;  a3 = cf >= 1.5f ? A3[2] : a3;
      a0 = cf >= 2.5f ? A0[3] : a0;  a1 = cf >= 2.5f ? A1[3] : a1;
      a2 = cf >= 2.5f ? A2[3] : a2;  a3 = cf >= 2.5f ? A3[3] : a3;
      a0 = cf >= 3.5f ? A0[4] : a0;  a1 = cf >= 3.5f ? A1[4] : a1;
      a2 = cf >= 3.5f ? A2[4] : a2;  a3 = cf >= 3.5f ? A3[4] : a3;
      float spl = fmaf(fmaf(fmaf(a3, u, a2), u, a1), u, a0);  // includes -Bnd
      float kan = fmaf(bw, sil, spl);
      float pr  = __expf(kan);
      ssum += pr;
      p[m] = pr;
    }

    // ---- PV: o[d] += p[m] * V[d][t0+m]  (V uniform -> SGPR broadcast) ----
    #pragma unroll
    for (int d = 0; d < DH; ++d) {
      const float* vr = Vb + (size_t)d * NPOS + t0;
      float acc0 = 0.f, acc1 = 0.f;
      #pragma unroll
      for (int m = 0; m < MT; m += 2) {
        acc0 = fmaf(p[m],     vr[m],     acc0);
        acc1 = fmaf(p[m + 1], vr[m + 1], acc1);
      }
      o[d] += acc0 + acc1;
    }
  }

  // ---- accumulate partials: Oacc [bh][d][n], Sden [bh][n] ----
  float* obase = Oacc + (size_t)bh * DH * NPOS;
  #pragma unroll
  for (int d = 0; d < DH; ++d)
    atomicAdd(obase + (size_t)d * NPOS + row, o[d]);
  atomicAdd(Sden + (size_t)bh * NPOS + row, ssum);
}

// ---------------------------------------------------------------------------
// Kernel C: output projection with fused normalization.
// out[b,c,n] = sum_i Wo[c,i] * Oacc[b*128+i][n] / Sden[b*4 + i/32][n]
// ---------------------------------------------------------------------------
__global__ __launch_bounds__(256) void outproj_kernel(
    const float* __restrict__ Oacc, const float* __restrict__ Sden,
    const float* __restrict__ Wo, float* __restrict__ out)
{
  const int lane = threadIdx.x & 63;
  const int it   = threadIdx.x >> 6;
  const int n    = blockIdx.x * 64 + lane;
  const int c0   = blockIdx.y * 16 + it * 4;   // blockIdx.y: 0..15
  const int b    = blockIdx.z;

  const float* ob = Oacc + (size_t)b * INNER * NPOS + n;
  const float* sd = Sden + (size_t)b * 4 * NPOS + n;
  const float* w0 = Wo + (size_t)c0 * INNER;

  float acc[4] = {0.f, 0.f, 0.f, 0.f};

  #pragma unroll
  for (int h = 0; h < 4; ++h) {
    const float si = __builtin_amdgcn_rcpf(sd[(size_t)h * NPOS]);
    #pragma unroll 8
    for (int i2 = 0; i2 < 32; ++i2) {
      const int i = h * 32 + i2;
      float xs = ob[(size_t)i * NPOS] * si;
      acc[0] += w0[i]             * xs;
      acc[1] += w0[INNER + i]     * xs;
      acc[2] += w0[2 * INNER + i] * xs;
      acc[3] += w0[3 * INNER + i] * xs;
    }
  }
  #pragma unroll
  for (int j = 0; j < 4; ++j)
    out[((size_t)(b * CH + c0 + j)) * NPOS + n] = acc[j];
}

// ---------------------------------------------------------------------------
extern "C" void kernel_launch(void* const* d_in, const int* in_sizes, int n_in,
                              void* d_out, int out_size, void* d_ws, size_t ws_size,
                              hipStream_t stream)
{
  const float* x  = (const float*)d_in[0];
  const float* Wq = (const float*)d_in[1];
  const float* Wk = (const float*)d_in[2];
  const float* Wv = (const float*)d_in[3];
  const float* Wo = (const float*)d_in[4];
  const float* bw = (const float*)d_in[5];
  const float* sw = (const float*)d_in[6];
  const float* ss = (const float*)d_in[7];
  float* out = (float*)d_out;
  float* ws  = (float*)d_ws;

  // workspace layout (floats): Oacc[8*32*1024] | Sden[8*1024] | Q | K | V
  float* Oacc = ws;
  float* Sden = Oacc + (size_t)NBH * DH * NPOS;
  float* Q    = Sden + (size_t)NBH * NPOS;
  float* K    = Q + (size_t)NBH * NPOS * DH;
  float* V    = K + (size_t)NBH * NPOS * DH;

  // zero the atomic accumulators (Oacc + Sden are contiguous)
  hipMemsetAsync(Oacc, 0,
                 ((size_t)NBH * DH * NPOS + (size_t)NBH * NPOS) * sizeof(float),
                 stream);

  proj_kernel<<<dim3(16, 16, 2), 256, 0, stream>>>(x, Wq, Wk, Wv, Q, K, V);
  attn_kernel<<<dim3(8, 4, SPLITS), 256, 0, stream>>>(
      Q, K, V, bw, sw, ss, Oacc, Sden);
  outproj_kernel<<<dim3(16, 16, 2), 256, 0, stream>>>(Oacc, Sden, Wo, out);
}

// Round 8
// 82.799 us; speedup vs baseline: 1.4400x; 1.4400x over previous
//
#include <hip/hip_runtime.h>
#include <math.h>

#define NPOS 1024   // H*W
#define DH   32     // dim head
#define NBH  8      // B * HEADS
#define CH   256
#define INNER 128   // HEADS*DIM_HEAD

typedef __attribute__((ext_vector_type(4))) _Float16 half4;
typedef __attribute__((ext_vector_type(4))) float f32x4;

// Canonical CDNA 16x16x16 f16 MFMA.  A: row=l&15, k=4*(l>>4)+j.  B: col=l&15,
// same k ordering (symmetric -> any consistent k placement cancels).
// C/D: col=l&15, row=(l>>4)*4+reg (m89-verified formula, AMD calculator-consistent).
#define MFMA16(a, b, c) __builtin_amdgcn_mfma_f32_16x16x16f16((a), (b), (c), 0, 0, 0)

union h2u { _Float16 h; unsigned short u; };

__device__ __forceinline__ unsigned short f2h(float f) {
  h2u c; c.h = (_Float16)f; return c.u;
}
__device__ __forceinline__ float h2f(unsigned short u) {
  h2u c; c.u = u; return (float)c.h;
}
// one 16x16x16 A/B fragment: 4 contiguous f16 at (row = l&15)*stride + 4*(l>>4)
__device__ __forceinline__ half4 ldh4(const unsigned short* __restrict__ p) {
  union { half4 v; uint2 u; } r;
  r.u = *(const uint2*)p;
  return r.v;
}

// ---------------------------------------------------------------------------
// Kernel A: fused QKV projection + split-f16 encode.
// Qhi/Qlo/Khi/Klo: [bh][n][d] (d-contiguous).  Vthi/Vtlo: [bh][d][n].
// Q pre-scaled by 1/sqrt(dh).
// ---------------------------------------------------------------------------
__global__ __launch_bounds__(256) void proj_kernel(
    const float* __restrict__ x, const float* __restrict__ Wq,
    const float* __restrict__ Wk, const float* __restrict__ Wv,
    unsigned short* __restrict__ Qhi, unsigned short* __restrict__ Qlo,
    unsigned short* __restrict__ Khi, unsigned short* __restrict__ Klo,
    unsigned short* __restrict__ Vthi, unsigned short* __restrict__ Vtlo)
{
  const int lane = threadIdx.x & 63;
  const int it   = threadIdx.x >> 6;        // 0..3
  const int n    = blockIdx.x * 64 + lane;  // 0..1023
  const int i0   = blockIdx.y * 8 + it * 2; // even, 0..126
  const int b    = blockIdx.z;

  const float* xb = x  + (size_t)b * CH * NPOS + n;
  const float* wq = Wq + (size_t)i0 * CH;
  const float* wk = Wk + (size_t)i0 * CH;
  const float* wv = Wv + (size_t)i0 * CH;

  float aq0 = 0.f, aq1 = 0.f, ak0 = 0.f, ak1 = 0.f, av0 = 0.f, av1 = 0.f;

  #pragma unroll 16
  for (int c = 0; c < CH; ++c) {
    float xv = xb[(size_t)c * NPOS];
    aq0 += wq[c]      * xv;
    aq1 += wq[CH + c] * xv;
    ak0 += wk[c]      * xv;
    ak1 += wk[CH + c] * xv;
    av0 += wv[c]      * xv;
    av1 += wv[CH + c] * xv;
  }

  const float qs = 0.17677669529663687f;  // 1/sqrt(32)
  aq0 *= qs;  aq1 *= qs;

  const int h = i0 >> 5, d = i0 & 31, bh = b * 4 + h;

  unsigned short qh0 = f2h(aq0), qh1 = f2h(aq1);
  unsigned short ql0 = f2h(aq0 - h2f(qh0)), ql1 = f2h(aq1 - h2f(qh1));
  unsigned short kh0 = f2h(ak0), kh1 = f2h(ak1);
  unsigned short kl0 = f2h(ak0 - h2f(kh0)), kl1 = f2h(ak1 - h2f(kh1));
  unsigned short vh0 = f2h(av0), vh1 = f2h(av1);
  unsigned short vl0 = f2h(av0 - h2f(vh0)), vl1 = f2h(av1 - h2f(vh1));

  const size_t qk = ((size_t)bh * NPOS + n) * DH + d;   // d even -> 4B aligned
  *(unsigned int*)(Qhi + qk) = (unsigned int)qh0 | ((unsigned int)qh1 << 16);
  *(unsigned int*)(Qlo + qk) = (unsigned int)ql0 | ((unsigned int)ql1 << 16);
  *(unsigned int*)(Khi + qk) = (unsigned int)kh0 | ((unsigned int)kh1 << 16);
  *(unsigned int*)(Klo + qk) = (unsigned int)kl0 | ((unsigned int)kl1 << 16);

  const size_t vt = ((size_t)bh * DH + d) * NPOS + n;
  Vthi[vt]        = vh0;
  Vthi[vt + NPOS] = vh1;
  Vtlo[vt]        = vl0;
  Vtlo[vt + NPOS] = vl1;
}

// ---------------------------------------------------------------------------
// Kernel B: S = Q·K^T via split-f16 MFMA (hi·hi + hi·lo + lo·hi), KAN +
// exp(kan - Bnd) epilogue, store P as f16.
// Grid (bh=8, q-strip=64, k-half=2); wave w covers 128 keys.
// ---------------------------------------------------------------------------
__global__ __launch_bounds__(256) void score_kernel(
    const unsigned short* __restrict__ Qhi, const unsigned short* __restrict__ Qlo,
    const unsigned short* __restrict__ Khi, const unsigned short* __restrict__ Klo,
    const float* __restrict__ bwp, const float* __restrict__ swp,
    const float* __restrict__ ssp, unsigned short* __restrict__ Pmat)
{
  const int tid = threadIdx.x;
  const int l   = tid & 63;
  const int w   = tid >> 6;                     // 0..3
  const int bh  = blockIdx.x;                   // 0..7  (== XCD)
  const int q0  = blockIdx.y * 16;              // q strip
  const int kb  = blockIdx.z * 512 + w * 128;   // 8 tiles of 16 keys

  // ---- uniform KAN constants ----
  const float sc = ssp[0];
  const float bw = bwp[0];
  float C[8];
  #pragma unroll
  for (int j = 0; j < 8; ++j) C[j] = swp[j] * sc;
  float maxc = 0.f;
  #pragma unroll
  for (int j = 0; j < 8; ++j) maxc = fmaxf(maxc, fabsf(C[j]));
  const float Bnd = fabsf(bw) * 6.0f + maxc;    // >= max_x kan(x)

  float A0[5], A1[5], A2[5], A3[5];             // per-cell cubic; -Bnd in A0
  #pragma unroll
  for (int c = 0; c < 5; ++c) {
    A0[c] = (C[c] + 4.f * C[c+1] + C[c+2]) * (1.f / 6.f) - Bnd;
    A1[c] = (-3.f * C[c] + 3.f * C[c+2]) * (1.f / 6.f);
    A2[c] = (3.f * C[c] - 6.f * C[c+1] + 3.f * C[c+2]) * (1.f / 6.f);
    A3[c] = (-C[c] + 3.f * C[c+1] - 3.f * C[c+2] + C[c+3]) * (1.f / 6.f);
  }

  // ---- Q fragments (persistent): row q0 + (l&15), k blocks {0-15},{16-31} ----
  const size_t qb = ((size_t)bh * NPOS + q0 + (l & 15)) * DH;
  const int    ko = (l >> 4) * 4;
  const half4 Ah0 = ldh4(Qhi + qb + ko);
  const half4 Ah1 = ldh4(Qhi + qb + 16 + ko);
  const half4 Al0 = ldh4(Qlo + qb + ko);
  const half4 Al1 = ldh4(Qlo + qb + 16 + ko);

  for (int t = 0; t < 8; ++t) {
    const int k0 = kb + t * 16;
    const size_t kbo = ((size_t)bh * NPOS + k0 + (l & 15)) * DH;
    const half4 Bh0 = ldh4(Khi + kbo + ko);
    const half4 Bh1 = ldh4(Khi + kbo + 16 + ko);
    const half4 Bl0 = ldh4(Klo + kbo + ko);
    const half4 Bl1 = ldh4(Klo + kbo + 16 + ko);

    f32x4 acc = {0.f, 0.f, 0.f, 0.f};
    acc = MFMA16(Ah0, Bh0, acc);
    acc = MFMA16(Ah1, Bh1, acc);
    acc = MFMA16(Ah0, Bl0, acc);
    acc = MFMA16(Ah1, Bl1, acc);
    acc = MFMA16(Al0, Bh0, acc);
    acc = MFMA16(Al1, Bh1, acc);

    unsigned short pst[4];
    #pragma unroll
    for (int r = 0; r < 4; ++r) {
      float s = acc[r];
      s = fminf(fmaxf(s, -6.0f), 6.0f);
      float e   = __expf(-s);
      float sil = s * __builtin_amdgcn_rcpf(1.0f + e);
      float tt  = fmaf(s, (1.0f / 2.4f), 2.5f);   // (s+6)/2.4 in [0,5]
      float cf  = fminf(floorf(tt), 4.0f);
      float u   = tt - cf;
      float a0 = A0[0], a1 = A1[0], a2 = A2[0], a3 = A3[0];
      a0 = cf >= 0.5f ? A0[1] : a0;  a1 = cf >= 0.5f ? A1[1] : a1;
      a2 = cf >= 0.5f ? A2[1] : a2;  a3 = cf >= 0.5f ? A3[1] : a3;
      a0 = cf >= 1.5f ? A0[2] : a0;  a1 = cf >= 1.5f ? A1[2] : a1;
      a2 = cf >= 1.5f ? A2[2] : a2;  a3 = cf >= 1.5f ? A3[2] : a3;
      a0 = cf >= 2.5f ? A0[3] : a0;  a1 = cf >= 2.5f ? A1[3] : a1;
      a2 = cf >= 2.5f ? A2[3] : a2;  a3 = cf >= 2.5f ? A3[3] : a3;
      a0 = cf >= 3.5f ? A0[4] : a0;  a1 = cf >= 3.5f ? A1[4] : a1;
      a2 = cf >= 3.5f ? A2[4] : a2;  a3 = cf >= 3.5f ? A3[4] : a3;
      float spl = fmaf(fmaf(fmaf(a3, u, a2), u, a1), u, a0);  // includes -Bnd
      float kan = fmaf(bw, sil, spl);
      pst[r] = f2h(__expf(kan));
    }

    const size_t pb = ((size_t)bh * NPOS + q0 + (l >> 4) * 4) * NPOS
                    + (size_t)(k0 + (l & 15));
    Pmat[pb]            = pst[0];
    Pmat[pb +     NPOS] = pst[1];
    Pmat[pb + 2 * NPOS] = pst[2];
    Pmat[pb + 3 * NPOS] = pst[3];
  }
}

// ---------------------------------------------------------------------------
// Kernel C: O = P·V via MFMA over BOTH d-blocks (d 0-15 and 16-31);
// denominator = P·ones via MFMA (same C/D layout as numerator by
// construction).  Grid (bh=8, q-strip=64); wave w covers keys [w*256,+256).
// ---------------------------------------------------------------------------
__global__ __launch_bounds__(256) void pv_kernel(
    const unsigned short* __restrict__ Pmat,
    const unsigned short* __restrict__ Vthi, const unsigned short* __restrict__ Vtlo,
    float* __restrict__ Onorm)
{
  __shared__ float Dl[4][16][33];

  const int tid = threadIdx.x;
  const int l   = tid & 63;
  const int w   = tid >> 6;
  const int bh  = blockIdx.x;
  const int q0  = blockIdx.y * 16;
  const int ko  = (l >> 4) * 4;

  half4 one4;
  #pragma unroll
  for (int j = 0; j < 4; ++j) one4[j] = (_Float16)1.0f;

  const unsigned short* prow =
      Pmat + ((size_t)bh * NPOS + q0 + (l & 15)) * NPOS;        // A: m = l&15
  const unsigned short* vrh0 =
      Vthi + ((size_t)bh * DH + (l & 15)) * NPOS;               // B: d = l&15
  const unsigned short* vrl0 =
      Vtlo + ((size_t)bh * DH + (l & 15)) * NPOS;
  const unsigned short* vrh1 = vrh0 + (size_t)16 * NPOS;        // d = 16+(l&15)
  const unsigned short* vrl1 = vrl0 + (size_t)16 * NPOS;

  f32x4 accD0 = {0.f, 0.f, 0.f, 0.f};   // d 0..15
  f32x4 accD1 = {0.f, 0.f, 0.f, 0.f};   // d 16..31
  f32x4 accS  = {0.f, 0.f, 0.f, 0.f};   // row sums (denominator)

  for (int st = 0; st < 8; ++st) {
    const int k0 = w * 256 + st * 32 + ko;
    const half4 Pf0 = ldh4(prow + k0);
    const half4 Pf1 = ldh4(prow + k0 + 16);

    const half4 Vh00 = ldh4(vrh0 + k0);
    const half4 Vh01 = ldh4(vrh0 + k0 + 16);
    const half4 Vl00 = ldh4(vrl0 + k0);
    const half4 Vl01 = ldh4(vrl0 + k0 + 16);
    accD0 = MFMA16(Pf0, Vh00, accD0);
    accD0 = MFMA16(Pf1, Vh01, accD0);
    accD0 = MFMA16(Pf0, Vl00, accD0);
    accD0 = MFMA16(Pf1, Vl01, accD0);

    const half4 Vh10 = ldh4(vrh1 + k0);
    const half4 Vh11 = ldh4(vrh1 + k0 + 16);
    const half4 Vl10 = ldh4(vrl1 + k0);
    const half4 Vl11 = ldh4(vrl1 + k0 + 16);
    accD1 = MFMA16(Pf0, Vh10, accD1);
    accD1 = MFMA16(Pf1, Vh11, accD1);
    accD1 = MFMA16(Pf0, Vl10, accD1);
    accD1 = MFMA16(Pf1, Vl11, accD1);

    accS = MFMA16(Pf0, one4, accS);
    accS = MFMA16(Pf1, one4, accS);
  }

  #pragma unroll
  for (int r = 0; r < 4; ++r) {
    Dl[w][(l >> 4) * 4 + r][l & 15]        = accD0[r];
    Dl[w][(l >> 4) * 4 + r][16 + (l & 15)] = accD1[r];
  }
  if ((l & 15) == 0) {
    #pragma unroll
    for (int r = 0; r < 4; ++r)
      Dl[w][(l >> 4) * 4 + r][32] = accS[r];
  }
  __syncthreads();

  for (int idx = tid; idx < 512; idx += 256) {
    const int q = idx & 15, d = idx >> 4;
    float o = Dl[0][q][d] + Dl[1][q][d] + Dl[2][q][d] + Dl[3][q][d];
    float sden = Dl[0][q][32] + Dl[1][q][32] + Dl[2][q][32] + Dl[3][q][32];
    Onorm[((size_t)bh * DH + d) * NPOS + q0 + q] = o / sden;
  }
}

// ---------------------------------------------------------------------------
// Kernel D: output projection. out[b,c,n] = sum_i Wo[c,i] * Onorm[b*128+i][n]
// ---------------------------------------------------------------------------
__global__ __launch_bounds__(256) void outproj_kernel(
    const float* __restrict__ Onorm, const float* __restrict__ Wo,
    float* __restrict__ out)
{
  const int lane = threadIdx.x & 63;
  const int it   = threadIdx.x >> 6;
  const int n    = blockIdx.x * 64 + lane;
  const int c0   = blockIdx.y * 16 + it * 4;   // blockIdx.y: 0..15
  const int b    = blockIdx.z;

  const float* ob = Onorm + (size_t)b * INNER * NPOS + n;
  const float* w0 = Wo + (size_t)c0 * INNER;

  float acc[4] = {0.f, 0.f, 0.f, 0.f};

  #pragma unroll 16
  for (int i = 0; i < INNER; ++i) {
    float xv = ob[(size_t)i * NPOS];
    acc[0] += w0[i]             * xv;
    acc[1] += w0[INNER + i]     * xv;
    acc[2] += w0[2 * INNER + i] * xv;
    acc[3] += w0[3 * INNER + i] * xv;
  }
  #pragma unroll
  for (int j = 0; j < 4; ++j)
    out[((size_t)(b * CH + c0 + j)) * NPOS + n] = acc[j];
}

// ---------------------------------------------------------------------------
extern "C" void kernel_launch(void* const* d_in, const int* in_sizes, int n_in,
                              void* d_out, int out_size, void* d_ws, size_t ws_size,
                              hipStream_t stream)
{
  const float* x  = (const float*)d_in[0];
  const float* Wq = (const float*)d_in[1];
  const float* Wk = (const float*)d_in[2];
  const float* Wv = (const float*)d_in[3];
  const float* Wo = (const float*)d_in[4];
  const float* bw = (const float*)d_in[5];
  const float* sw = (const float*)d_in[6];
  const float* ss = (const float*)d_in[7];
  float* out = (float*)d_out;

  // workspace: Onorm (f32, 1MB) | 6x f16 QKV (512KB each) | Pmat (f16, 16MB)
  float* Onorm = (float*)d_ws;
  unsigned short* base = (unsigned short*)(Onorm + (size_t)NBH * DH * NPOS);
  const size_t QKN = (size_t)NBH * NPOS * DH;   // 262144 elements
  unsigned short* Qhi  = base;
  unsigned short* Qlo  = Qhi  + QKN;
  unsigned short* Khi  = Qlo  + QKN;
  unsigned short* Klo  = Khi  + QKN;
  unsigned short* Vthi = Klo  + QKN;
  unsigned short* Vtlo = Vthi + QKN;
  unsigned short* Pmat = Vtlo + QKN;            // 8*1024*1024

  proj_kernel<<<dim3(16, 16, 2), 256, 0, stream>>>(
      x, Wq, Wk, Wv, Qhi, Qlo, Khi, Klo, Vthi, Vtlo);
  score_kernel<<<dim3(8, 64, 2), 256, 0, stream>>>(
      Qhi, Qlo, Khi, Klo, bw, sw, ss, Pmat);
  pv_kernel<<<dim3(8, 64, 1), 256, 0, stream>>>(Pmat, Vthi, Vtlo, Onorm);
  outproj_kernel<<<dim3(16, 16, 2), 256, 0, stream>>>(Onorm, Wo, out);
}

// Round 9
// 72.550 us; speedup vs baseline: 1.6434x; 1.1413x over previous
//
#include <hip/hip_runtime.h>
#include <math.h>

#define NPOS 1024   // H*W
#define DH   32     // dim head
#define NBH  8      // B * HEADS
#define CH   256
#define INNER 128   // HEADS*DIM_HEAD

typedef __attribute__((ext_vector_type(4))) _Float16 half4;
typedef __attribute__((ext_vector_type(4))) float f32x4;

// Canonical CDNA 16x16x16 f16 MFMA.  A: row=l&15, k=4*(l>>4)+j.  B: col=l&15,
// same k ordering.  C/D: col=l&15, row=(l>>4)*4+reg.
#define MFMA16(a, b, c) __builtin_amdgcn_mfma_f32_16x16x16f16((a), (b), (c), 0, 0, 0)

union h2u { _Float16 h; unsigned short u; };

__device__ __forceinline__ unsigned short f2h(float f) {
  h2u c; c.h = (_Float16)f; return c.u;
}
__device__ __forceinline__ float h2f(unsigned short u) {
  h2u c; c.u = u; return (float)c.h;
}
__device__ __forceinline__ half4 ldh4(const unsigned short* __restrict__ p) {
  union { half4 v; uint2 u; } r;
  r.u = *(const uint2*)p;
  return r.v;
}

// ---------------------------------------------------------------------------
// Kernel A: fused QKV projection + split-f16 encode.
// Qhi/Qlo/Khi/Klo: [bh][n][d] (d-contiguous).  Vthi/Vtlo: [bh][d][n].
// Q pre-scaled by 1/sqrt(dh).
// ---------------------------------------------------------------------------
__global__ __launch_bounds__(256) void proj_kernel(
    const float* __restrict__ x, const float* __restrict__ Wq,
    const float* __restrict__ Wk, const float* __restrict__ Wv,
    unsigned short* __restrict__ Qhi, unsigned short* __restrict__ Qlo,
    unsigned short* __restrict__ Khi, unsigned short* __restrict__ Klo,
    unsigned short* __restrict__ Vthi, unsigned short* __restrict__ Vtlo)
{
  const int lane = threadIdx.x & 63;
  const int it   = threadIdx.x >> 6;        // 0..3
  const int n    = blockIdx.x * 64 + lane;  // 0..1023
  const int i0   = blockIdx.y * 8 + it * 2; // even, 0..126
  const int b    = blockIdx.z;

  const float* xb = x  + (size_t)b * CH * NPOS + n;
  const float* wq = Wq + (size_t)i0 * CH;
  const float* wk = Wk + (size_t)i0 * CH;
  const float* wv = Wv + (size_t)i0 * CH;

  float aq0 = 0.f, aq1 = 0.f, ak0 = 0.f, ak1 = 0.f, av0 = 0.f, av1 = 0.f;

  #pragma unroll 16
  for (int c = 0; c < CH; ++c) {
    float xv = xb[(size_t)c * NPOS];
    aq0 += wq[c]      * xv;
    aq1 += wq[CH + c] * xv;
    ak0 += wk[c]      * xv;
    ak1 += wk[CH + c] * xv;
    av0 += wv[c]      * xv;
    av1 += wv[CH + c] * xv;
  }

  const float qs = 0.17677669529663687f;  // 1/sqrt(32)
  aq0 *= qs;  aq1 *= qs;

  const int h = i0 >> 5, d = i0 & 31, bh = b * 4 + h;

  unsigned short qh0 = f2h(aq0), qh1 = f2h(aq1);
  unsigned short ql0 = f2h(aq0 - h2f(qh0)), ql1 = f2h(aq1 - h2f(qh1));
  unsigned short kh0 = f2h(ak0), kh1 = f2h(ak1);
  unsigned short kl0 = f2h(ak0 - h2f(kh0)), kl1 = f2h(ak1 - h2f(kh1));
  unsigned short vh0 = f2h(av0), vh1 = f2h(av1);
  unsigned short vl0 = f2h(av0 - h2f(vh0)), vl1 = f2h(av1 - h2f(vh1));

  const size_t qk = ((size_t)bh * NPOS + n) * DH + d;   // d even -> 4B aligned
  *(unsigned int*)(Qhi + qk) = (unsigned int)qh0 | ((unsigned int)qh1 << 16);
  *(unsigned int*)(Qlo + qk) = (unsigned int)ql0 | ((unsigned int)ql1 << 16);
  *(unsigned int*)(Khi + qk) = (unsigned int)kh0 | ((unsigned int)kh1 << 16);
  *(unsigned int*)(Klo + qk) = (unsigned int)kl0 | ((unsigned int)kl1 << 16);

  const size_t vt = ((size_t)bh * DH + d) * NPOS + n;
  Vthi[vt]        = vh0;
  Vthi[vt + NPOS] = vh1;
  Vtlo[vt]        = vl0;
  Vtlo[vt + NPOS] = vl1;
}

// ---------------------------------------------------------------------------
// Kernel B: fully fused attention.  Per (bh, 16-q strip): 8 waves each own
// 128 keys.  S^T = K·Q^T (A=K, B=Q) -> lane holds S[q=l&15][k0+4*(l>>4)+r];
// KAN + exp(kan-Bnd) in-register; f16 P is directly the B-operand fragment
// for O^T = V^T·P^T.  Denominator sums the SAME f16-rounded p (consistency
// -> softmax rounding cancels).  8-way LDS combine, normalize, write Onorm.
// ---------------------------------------------------------------------------
__global__ __launch_bounds__(512) void attn_fused(
    const unsigned short* __restrict__ Qhi, const unsigned short* __restrict__ Qlo,
    const unsigned short* __restrict__ Khi, const unsigned short* __restrict__ Klo,
    const unsigned short* __restrict__ Vthi, const unsigned short* __restrict__ Vtlo,
    const float* __restrict__ bwp, const float* __restrict__ swp,
    const float* __restrict__ ssp, float* __restrict__ Onorm)
{
  __shared__ float DlO[8][32][17];
  __shared__ float DlS[8][4][17];

  const int tid = threadIdx.x;
  const int l   = tid & 63;
  const int w   = tid >> 6;        // 0..7
  const int lr  = l & 15;
  const int lg  = l >> 4;          // 0..3
  const int ko  = lg * 4;
  const int bh  = blockIdx.x;      // 0..7 (== XCD)
  const int q0  = blockIdx.y * 16;

  // ---- uniform KAN constants ----
  const float sc = ssp[0];
  const float bw = bwp[0];
  float C[8];
  #pragma unroll
  for (int j = 0; j < 8; ++j) C[j] = swp[j] * sc;
  float maxc = 0.f;
  #pragma unroll
  for (int j = 0; j < 8; ++j) maxc = fmaxf(maxc, fabsf(C[j]));
  const float Bnd = fabsf(bw) * 6.0f + maxc;    // >= max_x kan(x)

  float A0[5], A1[5], A2[5], A3[5];             // per-cell cubic; -Bnd in A0
  #pragma unroll
  for (int c = 0; c < 5; ++c) {
    A0[c] = (C[c] + 4.f * C[c+1] + C[c+2]) * (1.f / 6.f) - Bnd;
    A1[c] = (-3.f * C[c] + 3.f * C[c+2]) * (1.f / 6.f);
    A2[c] = (3.f * C[c] - 6.f * C[c+1] + 3.f * C[c+2]) * (1.f / 6.f);
    A3[c] = (-C[c] + 3.f * C[c+1] - 3.f * C[c+2] + C[c+3]) * (1.f / 6.f);
  }

  // ---- Q fragments (B-operand, persistent): col q = q0+lr, k-dim d ----
  const size_t qb = ((size_t)bh * NPOS + q0 + lr) * DH;
  const half4 Bq_h0 = ldh4(Qhi + qb + ko);
  const half4 Bq_h1 = ldh4(Qhi + qb + 16 + ko);
  const half4 Bq_l0 = ldh4(Qlo + qb + ko);
  const half4 Bq_l1 = ldh4(Qlo + qb + 16 + ko);

  // ---- V^T bases (A-operand): row d = lr (+16), k = key ----
  const unsigned short* vh0 = Vthi + ((size_t)bh * DH + lr) * NPOS;
  const unsigned short* vh1 = vh0 + (size_t)16 * NPOS;
  const unsigned short* vl0 = Vtlo + ((size_t)bh * DH + lr) * NPOS;
  const unsigned short* vl1 = vl0 + (size_t)16 * NPOS;

  f32x4 accO0 = {0.f, 0.f, 0.f, 0.f};   // d 0..15
  f32x4 accO1 = {0.f, 0.f, 0.f, 0.f};   // d 16..31
  float ssum = 0.f;

  #pragma unroll 2
  for (int t = 0; t < 8; ++t) {
    const int k0 = w * 128 + t * 16;

    // ---- QK: A = K rows k0+lr ----
    const size_t kb2 = ((size_t)bh * NPOS + k0 + lr) * DH;
    const half4 Ak_h0 = ldh4(Khi + kb2 + ko);
    const half4 Ak_h1 = ldh4(Khi + kb2 + 16 + ko);
    const half4 Ak_l0 = ldh4(Klo + kb2 + ko);
    const half4 Ak_l1 = ldh4(Klo + kb2 + 16 + ko);

    f32x4 acc = {0.f, 0.f, 0.f, 0.f};
    acc = MFMA16(Ak_h0, Bq_h0, acc);
    acc = MFMA16(Ak_h1, Bq_h1, acc);
    acc = MFMA16(Ak_h0, Bq_l0, acc);
    acc = MFMA16(Ak_h1, Bq_l1, acc);
    acc = MFMA16(Ak_l0, Bq_h0, acc);
    acc = MFMA16(Ak_l1, Bq_h1, acc);
    // acc[r] = S[q=q0+lr][k = k0+4*lg+r]

    // ---- KAN + exp(kan - Bnd) on 4 values; keep f16-consistent p ----
    unsigned short ph[4];
    #pragma unroll
    for (int r = 0; r < 4; ++r) {
      float s = acc[r];
      s = fminf(fmaxf(s, -6.0f), 6.0f);
      float e   = __expf(-s);
      float sil = s * __builtin_amdgcn_rcpf(1.0f + e);
      float tt  = fmaf(s, (1.0f / 2.4f), 2.5f);   // (s+6)/2.4 in [0,5]
      float cf  = fminf(floorf(tt), 4.0f);
      float u   = tt - cf;
      float a0 = A0[0], a1 = A1[0], a2 = A2[0], a3 = A3[0];
      a0 = cf >= 0.5f ? A0[1] : a0;  a1 = cf >= 0.5f ? A1[1] : a1;
      a2 = cf >= 0.5f ? A2[1] : a2;  a3 = cf >= 0.5f ? A3[1] : a3;
      a0 = cf >= 1.5f ? A0[2] : a0;  a1 = cf >= 1.5f ? A1[2] : a1;
      a2 = cf >= 1.5f ? A2[2] : a2;  a3 = cf >= 1.5f ? A3[2] : a3;
      a0 = cf >= 2.5f ? A0[3] : a0;  a1 = cf >= 2.5f ? A1[3] : a1;
      a2 = cf >= 2.5f ? A2[3] : a2;  a3 = cf >= 2.5f ? A3[3] : a3;
      a0 = cf >= 3.5f ? A0[4] : a0;  a1 = cf >= 3.5f ? A1[4] : a1;
      a2 = cf >= 3.5f ? A2[4] : a2;  a3 = cf >= 3.5f ? A3[4] : a3;
      float spl = fmaf(fmaf(fmaf(a3, u, a2), u, a1), u, a0);  // includes -Bnd
      float kan = fmaf(bw, sil, spl);
      unsigned short pu = f2h(__expf(kan));
      ph[r] = pu;
      ssum += h2f(pu);          // SAME rounded value PV consumes
    }
    union { half4 v; unsigned int u[2]; } Pb;
    Pb.u[0] = (unsigned int)ph[0] | ((unsigned int)ph[1] << 16);
    Pb.u[1] = (unsigned int)ph[2] | ((unsigned int)ph[3] << 16);
    // Pb is the B-operand fragment: col q = lr, k-elem j = key k0+4*lg+j

    // ---- PV: O^T += V^T · P^T  (A = V^T rows d=lr / 16+lr) ----
    const half4 Av_h0 = ldh4(vh0 + k0 + ko);
    const half4 Av_l0 = ldh4(vl0 + k0 + ko);
    const half4 Av_h1 = ldh4(vh1 + k0 + ko);
    const half4 Av_l1 = ldh4(vl1 + k0 + ko);
    accO0 = MFMA16(Av_h0, Pb.v, accO0);
    accO0 = MFMA16(Av_l0, Pb.v, accO0);
    accO1 = MFMA16(Av_h1, Pb.v, accO1);
    accO1 = MFMA16(Av_l1, Pb.v, accO1);
  }

  // ---- 8-way combine ----
  #pragma unroll
  for (int r = 0; r < 4; ++r) {
    DlO[w][4 * lg + r][lr]      = accO0[r];   // accO[r]: d = 4*lg+r, q = lr
    DlO[w][16 + 4 * lg + r][lr] = accO1[r];
  }
  DlS[w][lg][lr] = ssum;
  __syncthreads();

  {
    const int q = tid & 15;
    const int d = tid >> 4;     // 0..31 (512 threads)
    float o = 0.f, sden = 0.f;
    #pragma unroll
    for (int ww = 0; ww < 8; ++ww) {
      o += DlO[ww][d][q];
      #pragma unroll
      for (int g = 0; g < 4; ++g) sden += DlS[ww][g][q];
    }
    Onorm[((size_t)bh * DH + d) * NPOS + q0 + q] = o / sden;
  }
}

// ---------------------------------------------------------------------------
// Kernel C: output projection. out[b,c,n] = sum_i Wo[c,i] * Onorm[b*128+i][n]
// ---------------------------------------------------------------------------
__global__ __launch_bounds__(256) void outproj_kernel(
    const float* __restrict__ Onorm, const float* __restrict__ Wo,
    float* __restrict__ out)
{
  const int lane = threadIdx.x & 63;
  const int it   = threadIdx.x >> 6;
  const int n    = blockIdx.x * 64 + lane;
  const int c0   = blockIdx.y * 16 + it * 4;   // blockIdx.y: 0..15
  const int b    = blockIdx.z;

  const float* ob = Onorm + (size_t)b * INNER * NPOS + n;
  const float* w0 = Wo + (size_t)c0 * INNER;

  float acc[4] = {0.f, 0.f, 0.f, 0.f};

  #pragma unroll 16
  for (int i = 0; i < INNER; ++i) {
    float xv = ob[(size_t)i * NPOS];
    acc[0] += w0[i]             * xv;
    acc[1] += w0[INNER + i]     * xv;
    acc[2] += w0[2 * INNER + i] * xv;
    acc[3] += w0[3 * INNER + i] * xv;
  }
  #pragma unroll
  for (int j = 0; j < 4; ++j)
    out[((size_t)(b * CH + c0 + j)) * NPOS + n] = acc[j];
}

// ---------------------------------------------------------------------------
extern "C" void kernel_launch(void* const* d_in, const int* in_sizes, int n_in,
                              void* d_out, int out_size, void* d_ws, size_t ws_size,
                              hipStream_t stream)
{
  const float* x  = (const float*)d_in[0];
  const float* Wq = (const float*)d_in[1];
  const float* Wk = (const float*)d_in[2];
  const float* Wv = (const float*)d_in[3];
  const float* Wo = (const float*)d_in[4];
  const float* bw = (const float*)d_in[5];
  const float* sw = (const float*)d_in[6];
  const float* ss = (const float*)d_in[7];
  float* out = (float*)d_out;

  // workspace: Onorm (f32, 1MB) | 6x f16 QKV (512KB each)
  float* Onorm = (float*)d_ws;
  unsigned short* base = (unsigned short*)(Onorm + (size_t)NBH * DH * NPOS);
  const size_t QKN = (size_t)NBH * NPOS * DH;   // 262144 elements
  unsigned short* Qhi  = base;
  unsigned short* Qlo  = Qhi  + QKN;
  unsigned short* Khi  = Qlo  + QKN;
  unsigned short* Klo  = Khi  + QKN;
  unsigned short* Vthi = Klo  + QKN;
  unsigned short* Vtlo = Vthi + QKN;

  proj_kernel<<<dim3(16, 16, 2), 256, 0, stream>>>(
      x, Wq, Wk, Wv, Qhi, Qlo, Khi, Klo, Vthi, Vtlo);
  attn_fused<<<dim3(8, 64), 512, 0, stream>>>(
      Qhi, Qlo, Khi, Klo, Vthi, Vtlo, bw, sw, ss, Onorm);
  outproj_kernel<<<dim3(16, 16, 2), 256, 0, stream>>>(Onorm, Wo, out);
}

// Round 10
// 61.961 us; speedup vs baseline: 1.9242x; 1.1709x over previous
//
#include <hip/hip_runtime.h>
#include <math.h>

#define NPOS 1024   // H*W
#define DH   32     // dim head
#define NBH  8      // B * HEADS
#define CH   256
#define INNER 128   // HEADS*DIM_HEAD

typedef __attribute__((ext_vector_type(4))) _Float16 half4;
typedef __attribute__((ext_vector_type(4))) float f32x4;

// Canonical CDNA 16x16x16 f16 MFMA.  A: row=l&15, k=4*(l>>4)+j.  B: col=l&15,
// same k ordering.  C/D: col=l&15, row=(l>>4)*4+reg.
#define MFMA16(a, b, c) __builtin_amdgcn_mfma_f32_16x16x16f16((a), (b), (c), 0, 0, 0)

union h2u { _Float16 h; unsigned short u; };

__device__ __forceinline__ unsigned short f2h(float f) {
  h2u c; c.h = (_Float16)f; return c.u;
}
__device__ __forceinline__ float h2f(unsigned short u) {
  h2u c; c.u = u; return (float)c.h;
}
__device__ __forceinline__ half4 ldh4(const unsigned short* __restrict__ p) {
  union { half4 v; uint2 u; } r;
  r.u = *(const uint2*)p;
  return r.v;
}

// ---------------------------------------------------------------------------
// Kernel A: fused QKV projection + split-f16 encode.
// Qhi/Qlo/Khi/Klo: [bh][n][d] (d-contiguous).  Vthi/Vtlo: [bh][d][n].
// Q pre-scaled by 1/sqrt(dh).
// KEY: it forced into SGPR via readfirstlane -> weight addresses provably
// wave-uniform -> s_load (SMEM pipe), inner loop = 1 VMEM + 6 FMA.
// ---------------------------------------------------------------------------
__global__ __launch_bounds__(256) void proj_kernel(
    const float* __restrict__ x, const float* __restrict__ Wq,
    const float* __restrict__ Wk, const float* __restrict__ Wv,
    unsigned short* __restrict__ Qhi, unsigned short* __restrict__ Qlo,
    unsigned short* __restrict__ Khi, unsigned short* __restrict__ Klo,
    unsigned short* __restrict__ Vthi, unsigned short* __restrict__ Vtlo)
{
  const int lane = threadIdx.x & 63;
  const int it   = __builtin_amdgcn_readfirstlane(threadIdx.x >> 6); // 0..3, SGPR
  const int n    = blockIdx.x * 64 + lane;  // 0..1023
  const int i0   = blockIdx.y * 8 + it * 2; // even, 0..126 (wave-uniform SGPR)
  const int b    = blockIdx.z;

  const float* xb = x  + (size_t)b * CH * NPOS + n;
  const float* wq = Wq + (size_t)i0 * CH;
  const float* wk = Wk + (size_t)i0 * CH;
  const float* wv = Wv + (size_t)i0 * CH;

  float aq0 = 0.f, aq1 = 0.f, ak0 = 0.f, ak1 = 0.f, av0 = 0.f, av1 = 0.f;

  #pragma unroll 16
  for (int c = 0; c < CH; ++c) {
    float xv = xb[(size_t)c * NPOS];
    aq0 += wq[c]      * xv;
    aq1 += wq[CH + c] * xv;
    ak0 += wk[c]      * xv;
    ak1 += wk[CH + c] * xv;
    av0 += wv[c]      * xv;
    av1 += wv[CH + c] * xv;
  }

  const float qs = 0.17677669529663687f;  // 1/sqrt(32)
  aq0 *= qs;  aq1 *= qs;

  const int h = i0 >> 5, d = i0 & 31, bh = b * 4 + h;

  unsigned short qh0 = f2h(aq0), qh1 = f2h(aq1);
  unsigned short ql0 = f2h(aq0 - h2f(qh0)), ql1 = f2h(aq1 - h2f(qh1));
  unsigned short kh0 = f2h(ak0), kh1 = f2h(ak1);
  unsigned short kl0 = f2h(ak0 - h2f(kh0)), kl1 = f2h(ak1 - h2f(kh1));
  unsigned short vh0 = f2h(av0), vh1 = f2h(av1);
  unsigned short vl0 = f2h(av0 - h2f(vh0)), vl1 = f2h(av1 - h2f(vh1));

  const size_t qk = ((size_t)bh * NPOS + n) * DH + d;   // d even -> 4B aligned
  *(unsigned int*)(Qhi + qk) = (unsigned int)qh0 | ((unsigned int)qh1 << 16);
  *(unsigned int*)(Qlo + qk) = (unsigned int)ql0 | ((unsigned int)ql1 << 16);
  *(unsigned int*)(Khi + qk) = (unsigned int)kh0 | ((unsigned int)kh1 << 16);
  *(unsigned int*)(Klo + qk) = (unsigned int)kl0 | ((unsigned int)kl1 << 16);

  const size_t vt = ((size_t)bh * DH + d) * NPOS + n;
  Vthi[vt]        = vh0;
  Vthi[vt + NPOS] = vh1;
  Vtlo[vt]        = vl0;
  Vtlo[vt + NPOS] = vl1;
}

// ---------------------------------------------------------------------------
// Kernel B: fully fused attention (UNCHANGED from passing R9 version).
// S^T = K·Q^T; KAN + exp(kan-Bnd) in-register; f16 P = B-operand fragment
// for O^T = V^T·P^T; denominator sums same f16-rounded p; 8-way LDS combine.
// ---------------------------------------------------------------------------
__global__ __launch_bounds__(512) void attn_fused(
    const unsigned short* __restrict__ Qhi, const unsigned short* __restrict__ Qlo,
    const unsigned short* __restrict__ Khi, const unsigned short* __restrict__ Klo,
    const unsigned short* __restrict__ Vthi, const unsigned short* __restrict__ Vtlo,
    const float* __restrict__ bwp, const float* __restrict__ swp,
    const float* __restrict__ ssp, float* __restrict__ Onorm)
{
  __shared__ float DlO[8][32][17];
  __shared__ float DlS[8][4][17];

  const int tid = threadIdx.x;
  const int l   = tid & 63;
  const int w   = tid >> 6;        // 0..7
  const int lr  = l & 15;
  const int lg  = l >> 4;          // 0..3
  const int ko  = lg * 4;
  const int bh  = blockIdx.x;      // 0..7 (== XCD)
  const int q0  = blockIdx.y * 16;

  // ---- uniform KAN constants ----
  const float sc = ssp[0];
  const float bw = bwp[0];
  float C[8];
  #pragma unroll
  for (int j = 0; j < 8; ++j) C[j] = swp[j] * sc;
  float maxc = 0.f;
  #pragma unroll
  for (int j = 0; j < 8; ++j) maxc = fmaxf(maxc, fabsf(C[j]));
  const float Bnd = fabsf(bw) * 6.0f + maxc;    // >= max_x kan(x)

  float A0[5], A1[5], A2[5], A3[5];             // per-cell cubic; -Bnd in A0
  #pragma unroll
  for (int c = 0; c < 5; ++c) {
    A0[c] = (C[c] + 4.f * C[c+1] + C[c+2]) * (1.f / 6.f) - Bnd;
    A1[c] = (-3.f * C[c] + 3.f * C[c+2]) * (1.f / 6.f);
    A2[c] = (3.f * C[c] - 6.f * C[c+1] + 3.f * C[c+2]) * (1.f / 6.f);
    A3[c] = (-C[c] + 3.f * C[c+1] - 3.f * C[c+2] + C[c+3]) * (1.f / 6.f);
  }

  // ---- Q fragments (B-operand, persistent): col q = q0+lr, k-dim d ----
  const size_t qb = ((size_t)bh * NPOS + q0 + lr) * DH;
  const half4 Bq_h0 = ldh4(Qhi + qb + ko);
  const half4 Bq_h1 = ldh4(Qhi + qb + 16 + ko);
  const half4 Bq_l0 = ldh4(Qlo + qb + ko);
  const half4 Bq_l1 = ldh4(Qlo + qb + 16 + ko);

  // ---- V^T bases (A-operand): row d = lr (+16), k = key ----
  const unsigned short* vh0 = Vthi + ((size_t)bh * DH + lr) * NPOS;
  const unsigned short* vh1 = vh0 + (size_t)16 * NPOS;
  const unsigned short* vl0 = Vtlo + ((size_t)bh * DH + lr) * NPOS;
  const unsigned short* vl1 = vl0 + (size_t)16 * NPOS;

  f32x4 accO0 = {0.f, 0.f, 0.f, 0.f};   // d 0..15
  f32x4 accO1 = {0.f, 0.f, 0.f, 0.f};   // d 16..31
  float ssum = 0.f;

  #pragma unroll 2
  for (int t = 0; t < 8; ++t) {
    const int k0 = w * 128 + t * 16;

    // ---- QK: A = K rows k0+lr ----
    const size_t kb2 = ((size_t)bh * NPOS + k0 + lr) * DH;
    const half4 Ak_h0 = ldh4(Khi + kb2 + ko);
    const half4 Ak_h1 = ldh4(Khi + kb2 + 16 + ko);
    const half4 Ak_l0 = ldh4(Klo + kb2 + ko);
    const half4 Ak_l1 = ldh4(Klo + kb2 + 16 + ko);

    f32x4 acc = {0.f, 0.f, 0.f, 0.f};
    acc = MFMA16(Ak_h0, Bq_h0, acc);
    acc = MFMA16(Ak_h1, Bq_h1, acc);
    acc = MFMA16(Ak_h0, Bq_l0, acc);
    acc = MFMA16(Ak_h1, Bq_l1, acc);
    acc = MFMA16(Ak_l0, Bq_h0, acc);
    acc = MFMA16(Ak_l1, Bq_h1, acc);
    // acc[r] = S[q=q0+lr][k = k0+4*lg+r]

    // ---- KAN + exp(kan - Bnd) on 4 values; keep f16-consistent p ----
    unsigned short ph[4];
    #pragma unroll
    for (int r = 0; r < 4; ++r) {
      float s = acc[r];
      s = fminf(fmaxf(s, -6.0f), 6.0f);
      float e   = __expf(-s);
      float sil = s * __builtin_amdgcn_rcpf(1.0f + e);
      float tt  = fmaf(s, (1.0f / 2.4f), 2.5f);   // (s+6)/2.4 in [0,5]
      float cf  = fminf(floorf(tt), 4.0f);
      float u   = tt - cf;
      float a0 = A0[0], a1 = A1[0], a2 = A2[0], a3 = A3[0];
      a0 = cf >= 0.5f ? A0[1] : a0;  a1 = cf >= 0.5f ? A1[1] : a1;
      a2 = cf >= 0.5f ? A2[1] : a2;  a3 = cf >= 0.5f ? A3[1] : a3;
      a0 = cf >= 1.5f ? A0[2] : a0;  a1 = cf >= 1.5f ? A1[2] : a1;
      a2 = cf >= 1.5f ? A2[2] : a2;  a3 = cf >= 1.5f ? A3[2] : a3;
      a0 = cf >= 2.5f ? A0[3] : a0;  a1 = cf >= 2.5f ? A1[3] : a1;
      a2 = cf >= 2.5f ? A2[3] : a2;  a3 = cf >= 2.5f ? A3[3] : a3;
      a0 = cf >= 3.5f ? A0[4] : a0;  a1 = cf >= 3.5f ? A1[4] : a1;
      a2 = cf >= 3.5f ? A2[4] : a2;  a3 = cf >= 3.5f ? A3[4] : a3;
      float spl = fmaf(fmaf(fmaf(a3, u, a2), u, a1), u, a0);  // includes -Bnd
      float kan = fmaf(bw, sil, spl);
      unsigned short pu = f2h(__expf(kan));
      ph[r] = pu;
      ssum += h2f(pu);          // SAME rounded value PV consumes
    }
    union { half4 v; unsigned int u[2]; } Pb;
    Pb.u[0] = (unsigned int)ph[0] | ((unsigned int)ph[1] << 16);
    Pb.u[1] = (unsigned int)ph[2] | ((unsigned int)ph[3] << 16);
    // Pb is the B-operand fragment: col q = lr, k-elem j = key k0+4*lg+j

    // ---- PV: O^T += V^T · P^T  (A = V^T rows d=lr / 16+lr) ----
    const half4 Av_h0 = ldh4(vh0 + k0 + ko);
    const half4 Av_l0 = ldh4(vl0 + k0 + ko);
    const half4 Av_h1 = ldh4(vh1 + k0 + ko);
    const half4 Av_l1 = ldh4(vl1 + k0 + ko);
    accO0 = MFMA16(Av_h0, Pb.v, accO0);
    accO0 = MFMA16(Av_l0, Pb.v, accO0);
    accO1 = MFMA16(Av_h1, Pb.v, accO1);
    accO1 = MFMA16(Av_l1, Pb.v, accO1);
  }

  // ---- 8-way combine ----
  #pragma unroll
  for (int r = 0; r < 4; ++r) {
    DlO[w][4 * lg + r][lr]      = accO0[r];   // accO[r]: d = 4*lg+r, q = lr
    DlO[w][16 + 4 * lg + r][lr] = accO1[r];
  }
  DlS[w][lg][lr] = ssum;
  __syncthreads();

  {
    const int q = tid & 15;
    const int d = tid >> 4;     // 0..31 (512 threads)
    float o = 0.f, sden = 0.f;
    #pragma unroll
    for (int ww = 0; ww < 8; ++ww) {
      o += DlO[ww][d][q];
      #pragma unroll
      for (int g = 0; g < 4; ++g) sden += DlS[ww][g][q];
    }
    Onorm[((size_t)bh * DH + d) * NPOS + q0 + q] = o / sden;
  }
}

// ---------------------------------------------------------------------------
// Kernel C: output projection. out[b,c,n] = sum_i Wo[c,i] * Onorm[b*128+i][n]
// Same scalarization: c0 wave-uniform via readfirstlane -> Wo s_loads.
// ---------------------------------------------------------------------------
__global__ __launch_bounds__(256) void outproj_kernel(
    const float* __restrict__ Onorm, const float* __restrict__ Wo,
    float* __restrict__ out)
{
  const int lane = threadIdx.x & 63;
  const int it   = __builtin_amdgcn_readfirstlane(threadIdx.x >> 6); // SGPR
  const int n    = blockIdx.x * 64 + lane;
  const int c0   = blockIdx.y * 16 + it * 4;   // wave-uniform SGPR
  const int b    = blockIdx.z;

  const float* ob = Onorm + (size_t)b * INNER * NPOS + n;
  const float* w0 = Wo + (size_t)c0 * INNER;

  float acc[4] = {0.f, 0.f, 0.f, 0.f};

  #pragma unroll 16
  for (int i = 0; i < INNER; ++i) {
    float xv = ob[(size_t)i * NPOS];
    acc[0] += w0[i]             * xv;
    acc[1] += w0[INNER + i]     * xv;
    acc[2] += w0[2 * INNER + i] * xv;
    acc[3] += w0[3 * INNER + i] * xv;
  }
  #pragma unroll
  for (int j = 0; j < 4; ++j)
    out[((size_t)(b * CH + c0 + j)) * NPOS + n] = acc[j];
}

// ---------------------------------------------------------------------------
extern "C" void kernel_launch(void* const* d_in, const int* in_sizes, int n_in,
                              void* d_out, int out_size, void* d_ws, size_t ws_size,
                              hipStream_t stream)
{
  const float* x  = (const float*)d_in[0];
  const float* Wq = (const float*)d_in[1];
  const float* Wk = (const float*)d_in[2];
  const float* Wv = (const float*)d_in[3];
  const float* Wo = (const float*)d_in[4];
  const float* bw = (const float*)d_in[5];
  const float* sw = (const float*)d_in[6];
  const float* ss = (const float*)d_in[7];
  float* out = (float*)d_out;

  // workspace: Onorm (f32, 1MB) | 6x f16 QKV (512KB each)
  float* Onorm = (float*)d_ws;
  unsigned short* base = (unsigned short*)(Onorm + (size_t)NBH * DH * NPOS);
  const size_t QKN = (size_t)NBH * NPOS * DH;   // 262144 elements
  unsigned short* Qhi  = base;
  unsigned short* Qlo  = Qhi  + QKN;
  unsigned short* Khi  = Qlo  + QKN;
  unsigned short* Klo  = Khi  + QKN;
  unsigned short* Vthi = Klo  + QKN;
  unsigned short* Vtlo = Vthi + QKN;

  proj_kernel<<<dim3(16, 16, 2), 256, 0, stream>>>(
      x, Wq, Wk, Wv, Qhi, Qlo, Khi, Klo, Vthi, Vtlo);
  attn_fused<<<dim3(8, 64), 512, 0, stream>>>(
      Qhi, Qlo, Khi, Klo, Vthi, Vtlo, bw, sw, ss, Onorm);
  outproj_kernel<<<dim3(16, 16, 2), 256, 0, stream>>>(Onorm, Wo, out);
}